// Round 3
// baseline (429.714 us; speedup 1.0000x reference)
//
#include <hip/hip_runtime.h>

// ResLSTM: B=4096 independent LSTM chains, T=512, H=32, scalar input per step.
// Mapping: one wave64 per batch element. Lane l computes gate rows l and l+64:
//   lanes 0..31:  row l = i-gate,  row l+64 = g-gate
//   lanes 32..63: row l = f-gate,  row l+64 = o-gate
// h[j] lives in lane j (j<32); broadcast via v_readlane.
//
// R2 fix: the compiler rematerializes plain global loads (R0/R1 both showed
// VGPR_Count=44 < 64 weight floats => W_hh re-fetched from L1 every step,
// ~85 extra instr/step). Empty inline-asm with "+v" makes each weight value
// opaque — it cannot be re-loaded, forcing true VGPR residency.

static constexpr int T_LEN = 512;
static constexpr int H = 32;

__device__ __forceinline__ float rl_c(float v, int l) {
    return __int_as_float(__builtin_amdgcn_readlane(__float_as_int(v), l));
}

// exp2-based sigmoid: sigmoid(x) = rcp(1 + exp2(x * -log2(e)))
__device__ __forceinline__ float sig_e2(float x_times_nlog2e) {
    return __builtin_amdgcn_rcpf(1.0f + __builtin_amdgcn_exp2f(x_times_nlog2e));
}

// Defeat rematerialization: value becomes the output of an opaque asm.
#define PIN4(v) asm("" : "+v"(v.x), "+v"(v.y), "+v"(v.z), "+v"(v.w))

__global__ __launch_bounds__(256, 4)
void reslstm_kernel(const float* __restrict__ x,
                    const float* __restrict__ W_ih,
                    const float* __restrict__ W_hh,
                    const float* __restrict__ b_ih,
                    const float* __restrict__ b_hh,
                    const float* __restrict__ W_fc,
                    const float* __restrict__ b_fc,
                    float* __restrict__ out, int B)
{
    const int lane = threadIdx.x & 63;
    const int wv   = threadIdx.x >> 6;
    const int b    = (blockIdx.x << 2) + wv;
    if (b >= B) return;                       // wave-uniform guard

    const int r0 = lane;                      // i (lanes<32) or f (lanes>=32)
    const int r1 = lane + 64;                 // g (lanes<32) or o (lanes>=32)

    // W_hh rows for this lane -> 16 float4 = 64 VGPRs, pinned via asm.
    const float4* pa = reinterpret_cast<const float4*>(W_hh + r0 * H);
    const float4* pb = reinterpret_cast<const float4*>(W_hh + r1 * H);
    float4 a0 = pa[0], a1 = pa[1], a2 = pa[2], a3 = pa[3],
           a4 = pa[4], a5 = pa[5], a6 = pa[6], a7 = pa[7];
    float4 q0 = pb[0], q1 = pb[1], q2 = pb[2], q3 = pb[3],
           q4 = pb[4], q5 = pb[5], q6 = pb[6], q7 = pb[7];
    PIN4(a0); PIN4(a1); PIN4(a2); PIN4(a3);
    PIN4(a4); PIN4(a5); PIN4(a6); PIN4(a7);
    PIN4(q0); PIN4(q1); PIN4(q2); PIN4(q3);
    PIN4(q4); PIN4(q5); PIN4(q6); PIN4(q7);

    float wih0  = W_ih[r0];
    float wih1  = W_ih[r1];
    float bias0 = b_ih[r0] + b_hh[r0];
    float bias1 = b_ih[r1] + b_hh[r1];
    asm("" : "+v"(wih0), "+v"(wih1), "+v"(bias0), "+v"(bias1));

    // Branchless tanh-vs-sigmoid for the r1 gate: tanh(x) = 2*sigmoid(2x)-1.
    // Fold the sigmoid's -log2(e) and the 2x into per-lane constants.
    const bool  lo = (lane < 32);
    constexpr float NL2E = -1.4426950408889634f;
    float e1 = lo ? 2.0f * NL2E : NL2E;  // exp2 arg scale for gate r1
    float s1 = lo ? 2.0f : 1.0f;
    float t1 = lo ? -1.0f : 0.0f;
    asm("" : "+v"(e1), "+v"(s1), "+v"(t1));

    float h = 0.0f, c = 0.0f;
    const float* xrow = x + (size_t)b * T_LEN;

#define MAC4(va, vq, K)                                                   \
    {                                                                     \
        const float h0 = rl_c(h, (K) + 0);                                \
        const float h1 = rl_c(h, (K) + 1);                                \
        const float h2 = rl_c(h, (K) + 2);                                \
        const float h3 = rl_c(h, (K) + 3);                                \
        aA  = __builtin_fmaf(va.x, h0, aA);                               \
        aB  = __builtin_fmaf(vq.x, h0, aB);                               \
        aA2 = __builtin_fmaf(va.y, h1, aA2);                              \
        aB2 = __builtin_fmaf(vq.y, h1, aB2);                              \
        aA  = __builtin_fmaf(va.z, h2, aA);                               \
        aB  = __builtin_fmaf(vq.z, h2, aB);                               \
        aA2 = __builtin_fmaf(va.w, h3, aA2);                              \
        aB2 = __builtin_fmaf(vq.w, h3, aB2);                              \
    }

    for (int tc = 0; tc < T_LEN / 64; ++tc) {
        const float xv = xrow[(tc << 6) + lane];   // coalesced 64-float chunk
        #pragma unroll 4
        for (int tt = 0; tt < 64; ++tt) {
            const float xt = rl_c(xv, tt);         // x[b][t], wave-uniform
            float aA  = __builtin_fmaf(xt, wih0, bias0);
            float aB  = __builtin_fmaf(xt, wih1, bias1);
            float aA2 = 0.0f, aB2 = 0.0f;
            MAC4(a0, q0, 0)  MAC4(a1, q1, 4)  MAC4(a2, q2, 8)  MAC4(a3, q3, 12)
            MAC4(a4, q4, 16) MAC4(a5, q5, 20) MAC4(a6, q6, 24) MAC4(a7, q7, 28)
            aA += aA2; aB += aB2;
            const float g0 = sig_e2(aA * NL2E);                       // i | f
            const float g1 = __builtin_fmaf(s1, sig_e2(aB * e1), t1); // g | o
            const float fo = __shfl_xor(g0, 32);   // lanes<32 get f[j]
            const float og = __shfl_xor(g1, 32);   // lanes<32 get o[j]
            // Only lanes<32 carry meaningful c,h; upper lanes compute bounded
            // garbage never read (h-readlanes touch lanes 0..31 only).
            c = __builtin_fmaf(fo, c, g0 * g1);                       // f*c + i*g
            const float th = __builtin_fmaf(2.0f, sig_e2(c * (2.0f * NL2E)), -1.0f);
            h = og * th;                                              // o*tanh(c)
        }
    }
#undef MAC4
#undef PIN4

    // out[b] = sum_j h[j]*W_fc[j] + b_fc  (butterfly reduce over the wave)
    float val = lo ? h * W_fc[lane & (H - 1)] : 0.0f;
    #pragma unroll
    for (int off = 32; off >= 1; off >>= 1)
        val += __shfl_xor(val, off);
    if (lane == 0) out[b] = val + b_fc[0];
}

extern "C" void kernel_launch(void* const* d_in, const int* in_sizes, int n_in,
                              void* d_out, int out_size, void* d_ws, size_t ws_size,
                              hipStream_t stream) {
    const float* x    = (const float*)d_in[0];
    const float* W_ih = (const float*)d_in[1];
    const float* W_hh = (const float*)d_in[2];
    const float* b_ih = (const float*)d_in[3];
    const float* b_hh = (const float*)d_in[4];
    const float* W_fc = (const float*)d_in[5];
    const float* b_fc = (const float*)d_in[6];
    float* out = (float*)d_out;
    const int B = in_sizes[0] / T_LEN;        // 4096
    dim3 block(256);                          // 4 waves = 4 batch elements
    dim3 grid((B + 3) / 4);                   // 1024 blocks -> 4 waves/SIMD
    reslstm_kernel<<<grid, block, 0, stream>>>(x, W_ih, W_hh, b_ih, b_hh,
                                               W_fc, b_fc, out, B);
}

// Round 4
// 360.975 us; speedup vs baseline: 1.1904x; 1.1904x over previous
//
#include <hip/hip_runtime.h>

// ResLSTM: B=4096, T=512, H=32. One wave64 per batch element.
// Lane l computes gate rows l and l+64:
//   lanes 0..31:  row l = i,  row l+64 = g
//   lanes 32..63: row l = f,  row l+64 = o
//
// R4: h-broadcast via LDS instead of 32 v_readlane/step. Lanes write h to a
// per-wave 64-slot LDS row (2-way bank aliasing = free), then ALL lanes read
// slots 0..31 as 8 ds_read_b128 same-address broadcasts (conflict-free).
// This removes the readlane->SGPR serialization (R3 evidence: 410 issue-cyc
// per step vs ~120 static count, dur invariant across register strategies)
// and gives FMAs plain-VGPR operands.

static constexpr int T_LEN = 512;
static constexpr int H = 32;

__device__ __forceinline__ float rl_c(float v, int l) {
    return __int_as_float(__builtin_amdgcn_readlane(__float_as_int(v), l));
}

// exp2-based sigmoid: sigmoid(x) = rcp(1 + exp2(x * -log2(e)))
__device__ __forceinline__ float sig_e2(float x_times_nlog2e) {
    return __builtin_amdgcn_rcpf(1.0f + __builtin_amdgcn_exp2f(x_times_nlog2e));
}

// Defeat rematerialization of the weight loads.
#define PIN4(v) asm("" : "+v"(v.x), "+v"(v.y), "+v"(v.z), "+v"(v.w))

__global__ __launch_bounds__(256, 4)
void reslstm_kernel(const float* __restrict__ x,
                    const float* __restrict__ W_ih,
                    const float* __restrict__ W_hh,
                    const float* __restrict__ b_ih,
                    const float* __restrict__ b_hh,
                    const float* __restrict__ W_fc,
                    const float* __restrict__ b_fc,
                    float* __restrict__ out, int B)
{
    __shared__ float hbuf[4][64];            // [wave][slot]; slots 32..63 dummy

    const int lane = threadIdx.x & 63;
    const int wv   = threadIdx.x >> 6;
    const int b    = (blockIdx.x << 2) + wv;
    if (b >= B) return;                       // wave-uniform guard

    const int r0 = lane;                      // i | f
    const int r1 = lane + 64;                 // g | o

    // W_hh rows for this lane -> 16 float4 = 64 VGPRs, pinned.
    const float4* pa = reinterpret_cast<const float4*>(W_hh + r0 * H);
    const float4* pb = reinterpret_cast<const float4*>(W_hh + r1 * H);
    float4 a0 = pa[0], a1 = pa[1], a2 = pa[2], a3 = pa[3],
           a4 = pa[4], a5 = pa[5], a6 = pa[6], a7 = pa[7];
    float4 q0 = pb[0], q1 = pb[1], q2 = pb[2], q3 = pb[3],
           q4 = pb[4], q5 = pb[5], q6 = pb[6], q7 = pb[7];
    PIN4(a0); PIN4(a1); PIN4(a2); PIN4(a3);
    PIN4(a4); PIN4(a5); PIN4(a6); PIN4(a7);
    PIN4(q0); PIN4(q1); PIN4(q2); PIN4(q3);
    PIN4(q4); PIN4(q5); PIN4(q6); PIN4(q7);

    const float wih0  = W_ih[r0];
    const float wih1  = W_ih[r1];
    const float bias0 = b_ih[r0] + b_hh[r0];
    const float bias1 = b_ih[r1] + b_hh[r1];

    // Branchless tanh-vs-sigmoid for the r1 gate: tanh(x)=2*sigmoid(2x)-1.
    const bool  lo = (lane < 32);
    constexpr float NL2E = -1.4426950408889634f;
    const float e1 = lo ? 2.0f * NL2E : NL2E;
    const float s1 = lo ? 2.0f : 1.0f;
    const float t1 = lo ? -1.0f : 0.0f;

    float h = 0.0f, c = 0.0f;
    hbuf[wv][lane] = 0.0f;                    // h0 = 0 (wave-synchronous)

    const float* xrow = x + (size_t)b * T_LEN;
    const float4* hb = reinterpret_cast<const float4*>(&hbuf[wv][0]);

#define MAC4(va, vq, hv)                                                  \
    aA  = __builtin_fmaf(va.x, hv.x, aA);                                 \
    aB  = __builtin_fmaf(vq.x, hv.x, aB);                                 \
    aA2 = __builtin_fmaf(va.y, hv.y, aA2);                                \
    aB2 = __builtin_fmaf(vq.y, hv.y, aB2);                                \
    aA  = __builtin_fmaf(va.z, hv.z, aA);                                 \
    aB  = __builtin_fmaf(vq.z, hv.z, aB);                                 \
    aA2 = __builtin_fmaf(va.w, hv.w, aA2);                                \
    aB2 = __builtin_fmaf(vq.w, hv.w, aB2);

    for (int tc = 0; tc < T_LEN / 64; ++tc) {
        const float xv = xrow[(tc << 6) + lane];   // coalesced 64-float chunk
        #pragma unroll 4
        for (int tt = 0; tt < 64; ++tt) {
            const float xt = rl_c(xv, tt);         // x[b][t], wave-uniform
            float aA  = __builtin_fmaf(xt, wih0, bias0);
            float aB  = __builtin_fmaf(xt, wih1, bias1);
            float aA2 = 0.0f, aB2 = 0.0f;
            // h(t-1) broadcast from LDS: same-address b128 reads, 2 groups
            // of 4 to cap live registers.
            {
                float4 h0 = hb[0], h1 = hb[1], h2 = hb[2], h3 = hb[3];
                MAC4(a0, q0, h0) MAC4(a1, q1, h1)
                MAC4(a2, q2, h2) MAC4(a3, q3, h3)
            }
            {
                float4 h4 = hb[4], h5 = hb[5], h6 = hb[6], h7 = hb[7];
                MAC4(a4, q4, h4) MAC4(a5, q5, h5)
                MAC4(a6, q6, h6) MAC4(a7, q7, h7)
            }
            aA += aA2; aB += aB2;
            const float g0 = sig_e2(aA * NL2E);                       // i | f
            const float g1 = __builtin_fmaf(s1, sig_e2(aB * e1), t1); // g | o
            const float fo = __shfl_xor(g0, 32);   // lanes<32 get f[j]
            const float og = __shfl_xor(g1, 32);   // lanes<32 get o[j]
            // lanes>=32 carry bounded garbage c,h; their h lands in dummy
            // LDS slots 32..63 which the b128 broadcasts never touch.
            c = __builtin_fmaf(fo, c, g0 * g1);                       // f*c+i*g
            const float th = __builtin_fmaf(2.0f, sig_e2(c * (2.0f * NL2E)), -1.0f);
            h = og * th;                                              // o*tanh(c)
            hbuf[wv][lane] = h;                    // publish for next step
        }
    }
#undef MAC4
#undef PIN4

    // out[b] = sum_j h[j]*W_fc[j] + b_fc  (butterfly reduce over the wave)
    float val = lo ? h * W_fc[lane & (H - 1)] : 0.0f;
    #pragma unroll
    for (int off = 32; off >= 1; off >>= 1)
        val += __shfl_xor(val, off);
    if (lane == 0) out[b] = val + b_fc[0];
}

extern "C" void kernel_launch(void* const* d_in, const int* in_sizes, int n_in,
                              void* d_out, int out_size, void* d_ws, size_t ws_size,
                              hipStream_t stream) {
    const float* x    = (const float*)d_in[0];
    const float* W_ih = (const float*)d_in[1];
    const float* W_hh = (const float*)d_in[2];
    const float* b_ih = (const float*)d_in[3];
    const float* b_hh = (const float*)d_in[4];
    const float* W_fc = (const float*)d_in[5];
    const float* b_fc = (const float*)d_in[6];
    float* out = (float*)d_out;
    const int B = in_sizes[0] / T_LEN;        // 4096
    dim3 block(256);                          // 4 waves = 4 batch elements
    dim3 grid((B + 3) / 4);                   // 1024 blocks -> 4 waves/SIMD
    reslstm_kernel<<<grid, block, 0, stream>>>(x, W_ih, W_hh, b_ih, b_hh,
                                               W_fc, b_fc, out, B);
}

// Round 5
// 360.387 us; speedup vs baseline: 1.1924x; 1.0016x over previous
//
#include <hip/hip_runtime.h>

// ResLSTM: B=4096, T=512, H=32. One wave64 per batch element.
// Lane l computes gate rows l and l+64:
//   lanes 0..31:  row l = i,  row l+64 = g
//   lanes 32..63: row l = f,  row l+64 = o
//
// R4 win: h-broadcast via LDS (8 same-address ds_read_b128) instead of 32
// v_readlane/step (407 -> 330 us).
// R5 fix: VGPR_Count was pinned at ~52 across 3 register strategies because
// the allocator's default pressure target is ~8 waves/EU (64-reg budget);
// __launch_bounds__(256,4) only sets a MINIMUM of 4 waves/EU. Clamp BOTH
// bounds with amdgpu_waves_per_eu(4,4) -> full 128-VGPR budget, weights can
// finally live in registers. Grid is exactly 4 blocks/CU so max=4 costs no
// real occupancy.

static constexpr int T_LEN = 512;
static constexpr int H = 32;

__device__ __forceinline__ float rl_c(float v, int l) {
    return __int_as_float(__builtin_amdgcn_readlane(__float_as_int(v), l));
}

// exp2-based sigmoid: sigmoid(x) = rcp(1 + exp2(x * -log2(e)))
__device__ __forceinline__ float sig_e2(float x_times_nlog2e) {
    return __builtin_amdgcn_rcpf(1.0f + __builtin_amdgcn_exp2f(x_times_nlog2e));
}

// Defeat rematerialization of the weight loads.
#define PIN4(v) asm("" : "+v"(v.x), "+v"(v.y), "+v"(v.z), "+v"(v.w))

__global__ void
__attribute__((amdgpu_flat_work_group_size(256, 256), amdgpu_waves_per_eu(4, 4)))
reslstm_kernel(const float* __restrict__ x,
               const float* __restrict__ W_ih,
               const float* __restrict__ W_hh,
               const float* __restrict__ b_ih,
               const float* __restrict__ b_hh,
               const float* __restrict__ W_fc,
               const float* __restrict__ b_fc,
               float* __restrict__ out, int B)
{
    __shared__ float hbuf[4][64];            // [wave][slot]; slots 32..63 dummy

    const int lane = threadIdx.x & 63;
    const int wv   = threadIdx.x >> 6;
    const int b    = (blockIdx.x << 2) + wv;
    if (b >= B) return;                       // wave-uniform guard

    const int r0 = lane;                      // i | f
    const int r1 = lane + 64;                 // g | o

    // W_hh rows for this lane -> 16 float4 = 64 VGPRs, pinned.
    const float4* pa = reinterpret_cast<const float4*>(W_hh + r0 * H);
    const float4* pb = reinterpret_cast<const float4*>(W_hh + r1 * H);
    float4 a0 = pa[0], a1 = pa[1], a2 = pa[2], a3 = pa[3],
           a4 = pa[4], a5 = pa[5], a6 = pa[6], a7 = pa[7];
    float4 q0 = pb[0], q1 = pb[1], q2 = pb[2], q3 = pb[3],
           q4 = pb[4], q5 = pb[5], q6 = pb[6], q7 = pb[7];
    PIN4(a0); PIN4(a1); PIN4(a2); PIN4(a3);
    PIN4(a4); PIN4(a5); PIN4(a6); PIN4(a7);
    PIN4(q0); PIN4(q1); PIN4(q2); PIN4(q3);
    PIN4(q4); PIN4(q5); PIN4(q6); PIN4(q7);

    const float wih0  = W_ih[r0];
    const float wih1  = W_ih[r1];
    const float bias0 = b_ih[r0] + b_hh[r0];
    const float bias1 = b_ih[r1] + b_hh[r1];

    // Branchless tanh-vs-sigmoid for the r1 gate: tanh(x)=2*sigmoid(2x)-1.
    const bool  lo = (lane < 32);
    constexpr float NL2E = -1.4426950408889634f;
    const float e1 = lo ? 2.0f * NL2E : NL2E;
    const float s1 = lo ? 2.0f : 1.0f;
    const float t1 = lo ? -1.0f : 0.0f;

    float h = 0.0f, c = 0.0f;
    hbuf[wv][lane] = 0.0f;                    // h0 = 0 (wave-synchronous)

    const float* xrow = x + (size_t)b * T_LEN;
    const float4* hb = reinterpret_cast<const float4*>(&hbuf[wv][0]);

#define MAC4(va, vq, hv)                                                  \
    aA  = __builtin_fmaf(va.x, hv.x, aA);                                 \
    aB  = __builtin_fmaf(vq.x, hv.x, aB);                                 \
    aA2 = __builtin_fmaf(va.y, hv.y, aA2);                                \
    aB2 = __builtin_fmaf(vq.y, hv.y, aB2);                                \
    aA  = __builtin_fmaf(va.z, hv.z, aA);                                 \
    aB  = __builtin_fmaf(vq.z, hv.z, aB);                                 \
    aA2 = __builtin_fmaf(va.w, hv.w, aA2);                                \
    aB2 = __builtin_fmaf(vq.w, hv.w, aB2);

    for (int tc = 0; tc < T_LEN / 64; ++tc) {
        const float xv = xrow[(tc << 6) + lane];   // coalesced 64-float chunk
        #pragma unroll 4
        for (int tt = 0; tt < 64; ++tt) {
            const float xt = rl_c(xv, tt);         // x[b][t], wave-uniform
            float aA  = __builtin_fmaf(xt, wih0, bias0);
            float aB  = __builtin_fmaf(xt, wih1, bias1);
            float aA2 = 0.0f, aB2 = 0.0f;
            // h(t-1) broadcast from LDS: same-address b128 reads (free
            // broadcast, no bank conflict), 2 groups of 4 to cap live regs.
            {
                float4 h0 = hb[0], h1 = hb[1], h2 = hb[2], h3 = hb[3];
                MAC4(a0, q0, h0) MAC4(a1, q1, h1)
                MAC4(a2, q2, h2) MAC4(a3, q3, h3)
            }
            {
                float4 h4 = hb[4], h5 = hb[5], h6 = hb[6], h7 = hb[7];
                MAC4(a4, q4, h4) MAC4(a5, q5, h5)
                MAC4(a6, q6, h6) MAC4(a7, q7, h7)
            }
            aA += aA2; aB += aB2;
            const float g0 = sig_e2(aA * NL2E);                       // i | f
            const float g1 = __builtin_fmaf(s1, sig_e2(aB * e1), t1); // g | o
            const float fo = __shfl_xor(g0, 32);   // lanes<32 get f[j]
            const float og = __shfl_xor(g1, 32);   // lanes<32 get o[j]
            // lanes>=32 carry bounded garbage c,h; their h lands in dummy
            // LDS slots 32..63 which the b128 broadcasts never touch.
            c = __builtin_fmaf(fo, c, g0 * g1);                       // f*c+i*g
            const float th = __builtin_fmaf(2.0f, sig_e2(c * (2.0f * NL2E)), -1.0f);
            h = og * th;                                              // o*tanh(c)
            hbuf[wv][lane] = h;                    // publish for next step
        }
    }
#undef MAC4
#undef PIN4

    // out[b] = sum_j h[j]*W_fc[j] + b_fc  (butterfly reduce over the wave)
    float val = lo ? h * W_fc[lane & (H - 1)] : 0.0f;
    #pragma unroll
    for (int off = 32; off >= 1; off >>= 1)
        val += __shfl_xor(val, off);
    if (lane == 0) out[b] = val + b_fc[0];
}

extern "C" void kernel_launch(void* const* d_in, const int* in_sizes, int n_in,
                              void* d_out, int out_size, void* d_ws, size_t ws_size,
                              hipStream_t stream) {
    const float* x    = (const float*)d_in[0];
    const float* W_ih = (const float*)d_in[1];
    const float* W_hh = (const float*)d_in[2];
    const float* b_ih = (const float*)d_in[3];
    const float* b_hh = (const float*)d_in[4];
    const float* W_fc = (const float*)d_in[5];
    const float* b_fc = (const float*)d_in[6];
    float* out = (float*)d_out;
    const int B = in_sizes[0] / T_LEN;        // 4096
    dim3 block(256);                          // 4 waves = 4 batch elements
    dim3 grid((B + 3) / 4);                   // 1024 blocks -> 4 waves/SIMD
    reslstm_kernel<<<grid, block, 0, stream>>>(x, W_ih, W_hh, b_ih, b_hh,
                                               W_fc, b_fc, out, B);
}

// Round 7
// 357.338 us; speedup vs baseline: 1.2025x; 1.0085x over previous
//
#include <hip/hip_runtime.h>

// ResLSTM: B=4096, T=512, H=32. One wave64 per batch element.
// Lane l computes gate rows l and l+64:
//   lanes 0..31:  row l = i,  row l+64 = g
//   lanes 32..63: row l = f,  row l+64 = o
//
// R4 win: h-broadcast via LDS (same-address ds_read_b128), 407 -> 330 us.
// R5: waves_per_eu(4,4) clamp -> 330 -> 316, VGPR 52 -> 60.
// R6: volatile in-loop pins (compile-failed on macro-name capture; R7 fixes
// the macro only). Rationale: non-volatile asm pins were sunk into the loop
// and re-executed with their feeding loads each step (16 KB/wave/step of L1
// traffic ~ 1024 cyc/step-group, matching the observed stall). A VOLATILE
// asm inside the innermost loop must execute exactly once per iteration and
// its output feeds the next iteration -> reload is illegal -> all 64 weight
// floats must stay VGPR-resident.

static constexpr int T_LEN = 512;
static constexpr int H = 32;

__device__ __forceinline__ float rl_c(float v, int l) {
    return __int_as_float(__builtin_amdgcn_readlane(__float_as_int(v), l));
}

// exp2-based sigmoid: sigmoid(x) = rcp(1 + exp2(x * -log2(e)))
__device__ __forceinline__ float sig_e2(float x_times_nlog2e) {
    return __builtin_amdgcn_rcpf(1.0f + __builtin_amdgcn_exp2f(x_times_nlog2e));
}

__global__ void
__attribute__((amdgpu_flat_work_group_size(256, 256), amdgpu_waves_per_eu(4, 4)))
reslstm_kernel(const float* __restrict__ x,
               const float* __restrict__ W_ih,
               const float* __restrict__ W_hh,
               const float* __restrict__ b_ih,
               const float* __restrict__ b_hh,
               const float* __restrict__ W_fc,
               const float* __restrict__ b_fc,
               float* __restrict__ out, int B)
{
    __shared__ float hbuf[4][64];            // [wave][slot]; slots 32..63 dummy

    const int lane = threadIdx.x & 63;
    const int wv   = threadIdx.x >> 6;
    const int b    = (blockIdx.x << 2) + wv;
    if (b >= B) return;                       // wave-uniform guard

    const int r0 = lane;                      // i | f
    const int r1 = lane + 64;                 // g | o

    // W_hh rows for this lane -> 16 float4 = 64 VGPRs.
    const float4* pa = reinterpret_cast<const float4*>(W_hh + r0 * H);
    const float4* pb = reinterpret_cast<const float4*>(W_hh + r1 * H);
    float4 a0 = pa[0], a1 = pa[1], a2 = pa[2], a3 = pa[3],
           a4 = pa[4], a5 = pa[5], a6 = pa[6], a7 = pa[7];
    float4 q0 = pb[0], q1 = pb[1], q2 = pb[2], q3 = pb[3],
           q4 = pb[4], q5 = pb[5], q6 = pb[6], q7 = pb[7];

    float wih0  = W_ih[r0];
    float wih1  = W_ih[r1];
    float bias0 = b_ih[r0] + b_hh[r0];
    float bias1 = b_ih[r1] + b_hh[r1];

    // Branchless tanh-vs-sigmoid for the r1 gate: tanh(x)=2*sigmoid(2x)-1.
    const bool  lo = (lane < 32);
    constexpr float NL2E = -1.4426950408889634f;
    float e1 = lo ? 2.0f * NL2E : NL2E;
    float s1 = lo ? 2.0f : 1.0f;
    float t1 = lo ? -1.0f : 0.0f;

    float h = 0.0f, c = 0.0f;
    hbuf[wv][lane] = 0.0f;                    // h0 = 0 (wave-synchronous)

    const float* xrow = x + (size_t)b * T_LEN;
    const float4* hb = reinterpret_cast<const float4*>(&hbuf[wv][0]);

// Volatile pins: executed once per iteration, output feeds next iteration.
// Reloading these values from memory is illegal -> they MUST stay in VGPRs.
// NOTE: macro parameter names P0..P3 deliberately avoid field names x/y/z/w
// (R6 compile failure was parameter 'w' capturing the '.w' field access).
#define PINV4x4(P0, P1, P2, P3)                                           \
    asm volatile("" : "+v"(P0.x), "+v"(P0.y), "+v"(P0.z), "+v"(P0.w),     \
                      "+v"(P1.x), "+v"(P1.y), "+v"(P1.z), "+v"(P1.w),     \
                      "+v"(P2.x), "+v"(P2.y), "+v"(P2.z), "+v"(P2.w),     \
                      "+v"(P3.x), "+v"(P3.y), "+v"(P3.z), "+v"(P3.w))
#define PINALL()                                                          \
    PINV4x4(a0, a1, a2, a3); PINV4x4(a4, a5, a6, a7);                     \
    PINV4x4(q0, q1, q2, q3); PINV4x4(q4, q5, q6, q7);                     \
    asm volatile("" : "+v"(wih0), "+v"(wih1), "+v"(bias0), "+v"(bias1),   \
                      "+v"(e1), "+v"(s1), "+v"(t1))

#define MAC4(va, vq, hv)                                                  \
    aA  = __builtin_fmaf(va.x, hv.x, aA);                                 \
    aB  = __builtin_fmaf(vq.x, hv.x, aB);                                 \
    aA2 = __builtin_fmaf(va.y, hv.y, aA2);                                \
    aB2 = __builtin_fmaf(vq.y, hv.y, aB2);                                \
    aA  = __builtin_fmaf(va.z, hv.z, aA);                                 \
    aB  = __builtin_fmaf(vq.z, hv.z, aB);                                 \
    aA2 = __builtin_fmaf(va.w, hv.w, aA2);                                \
    aB2 = __builtin_fmaf(vq.w, hv.w, aB2);

    for (int tc = 0; tc < T_LEN / 64; ++tc) {
        const float xv = xrow[(tc << 6) + lane];   // coalesced 64-float chunk
        #pragma unroll 4
        for (int tt = 0; tt < 64; ++tt) {
            PINALL();                              // force weight residency
            const float xt = rl_c(xv, tt);         // x[b][t], wave-uniform
            float aA  = __builtin_fmaf(xt, wih0, bias0);
            float aB  = __builtin_fmaf(xt, wih1, bias1);
            float aA2 = 0.0f, aB2 = 0.0f;
            // h(t-1) broadcast from LDS: same-address b128 reads (free
            // broadcast, no bank conflict), 2 groups of 4 to cap live regs.
            {
                float4 h0 = hb[0], h1 = hb[1], h2 = hb[2], h3 = hb[3];
                MAC4(a0, q0, h0) MAC4(a1, q1, h1)
                MAC4(a2, q2, h2) MAC4(a3, q3, h3)
            }
            {
                float4 h4 = hb[4], h5 = hb[5], h6 = hb[6], h7 = hb[7];
                MAC4(a4, q4, h4) MAC4(a5, q5, h5)
                MAC4(a6, q6, h6) MAC4(a7, q7, h7)
            }
            aA += aA2; aB += aB2;
            const float g0 = sig_e2(aA * NL2E);                       // i | f
            const float g1 = __builtin_fmaf(s1, sig_e2(aB * e1), t1); // g | o
            const float fo = __shfl_xor(g0, 32);   // lanes<32 get f[j]
            const float og = __shfl_xor(g1, 32);   // lanes<32 get o[j]
            // lanes>=32 carry bounded garbage c,h; their h lands in dummy
            // LDS slots 32..63 which the b128 broadcasts never touch.
            c = __builtin_fmaf(fo, c, g0 * g1);                       // f*c+i*g
            const float th = __builtin_fmaf(2.0f, sig_e2(c * (2.0f * NL2E)), -1.0f);
            h = og * th;                                              // o*tanh(c)
            hbuf[wv][lane] = h;                    // publish for next step
        }
    }
#undef MAC4
#undef PINALL
#undef PINV4x4

    // out[b] = sum_j h[j]*W_fc[j] + b_fc  (butterfly reduce over the wave)
    float val = lo ? h * W_fc[lane & (H - 1)] : 0.0f;
    #pragma unroll
    for (int off = 32; off >= 1; off >>= 1)
        val += __shfl_xor(val, off);
    if (lane == 0) out[b] = val + b_fc[0];
}

extern "C" void kernel_launch(void* const* d_in, const int* in_sizes, int n_in,
                              void* d_out, int out_size, void* d_ws, size_t ws_size,
                              hipStream_t stream) {
    const float* x    = (const float*)d_in[0];
    const float* W_ih = (const float*)d_in[1];
    const float* W_hh = (const float*)d_in[2];
    const float* b_ih = (const float*)d_in[3];
    const float* b_hh = (const float*)d_in[4];
    const float* W_fc = (const float*)d_in[5];
    const float* b_fc = (const float*)d_in[6];
    float* out = (float*)d_out;
    const int B = in_sizes[0] / T_LEN;        // 4096
    dim3 block(256);                          // 4 waves = 4 batch elements
    dim3 grid((B + 3) / 4);                   // 1024 blocks -> 4 waves/SIMD
    reslstm_kernel<<<grid, block, 0, stream>>>(x, W_ih, W_hh, b_ih, b_hh,
                                               W_fc, b_fc, out, B);
}